// Round 8
// baseline (31.122 us; speedup 1.0000x reference)
//
#include <hip/hip_runtime.h>

// B=4, T=16, N=S=256, H=8, DK=DV=64, fp32 in/out.
// One block per (bt, h): 512 blocks x 512 threads (8 waves).
// Swapped QK^T (A=K, B=Q), no max-sub, scale*log2e folded into Q,
// both n-passes merged (K/V LDS fragments read once), permlane P exchange,
// V^T XOR bank-swizzle, depth-1 K/V ds_read prefetch, per-wave ks stagger.
// This round: plain O stores (nontemporal caused partial-line RMW: 32->48MB).

typedef short short8 __attribute__((ext_vector_type(8)));
typedef float floatx4 __attribute__((ext_vector_type(4)));

__device__ __forceinline__ unsigned cvt_pk(float lo, float hi) {
  unsigned r;
  asm("v_cvt_pk_bf16_f32 %0, %1, %2" : "=v"(r) : "v"(lo), "v"(hi));
  return r;
}

constexpr int KSTR  = 72;    // Klds row stride in shorts (144 B)
constexpr int VSTRW = 132;   // Vt row stride in u32 words (528 B)

__global__ __launch_bounds__(512, 4) void attn_kernel(
    const float* __restrict__ Q, const float* __restrict__ K,
    const float* __restrict__ V, float* __restrict__ O) {
  __shared__ __align__(16) short Klds[256 * KSTR];       // 36864 B
  __shared__ __align__(16) unsigned Vt32[64 * VSTRW];    // 33792 B (70656 total)

  const int inst = blockIdx.x;
  const int h    = inst & 7;
  const int bt   = inst >> 3;
  const int base = bt * (256 * 512) + h * 64;
  const int tid  = threadIdx.x;

  // ---- stage K: 256x64 fp32 -> bf16 LDS ----
  {
    const float* Kb = K + base;
    #pragma unroll
    for (int i = 0; i < 8; ++i) {
      int idx = i * 512 + tid;
      int s = idx >> 4, c4 = idx & 15;
      float4 v = *reinterpret_cast<const float4*>(Kb + s * 512 + c4 * 4);
      uint2 w;
      w.x = cvt_pk(v.x, v.y);
      w.y = cvt_pk(v.z, v.w);
      *reinterpret_cast<uint2*>(&Klds[s * KSTR + c4 * 4]) = w;
    }
  }
  // ---- stage V^T with XOR bank swizzle: logical word col P stored at
  //      P ^ ((d>>2)&7)<<2  (write: d = 4*c4+k -> swz = (c4&7)<<2) ----
  {
    const float* Vb = V + base;
    #pragma unroll
    for (int i = 0; i < 4; ++i) {
      int idx = i * 512 + tid;
      int sp = idx >> 4, c4 = idx & 15;
      int s = sp * 2;
      int spw = sp ^ ((c4 & 7) << 2);
      float4 v0 = *reinterpret_cast<const float4*>(Vb + s * 512 + c4 * 4);
      float4 v1 = *reinterpret_cast<const float4*>(Vb + (s + 1) * 512 + c4 * 4);
      #pragma unroll
      for (int k = 0; k < 4; ++k) {
        Vt32[(c4 * 4 + k) * VSTRW + spw] = cvt_pk((&v0.x)[k], (&v1.x)[k]);
      }
    }
  }

  const int wave = tid >> 6;
  const int lane = tid & 63;
  const int c    = lane & 15;
  const int g    = lane >> 4;

  // ---- Q fragments for BOTH passes, scaled by 0.125*log2(e) ----
  const float SCQ = 0.125f * 1.4426950408889634f;
  short8 qf[2][2];
  #pragma unroll
  for (int p = 0; p < 2; ++p) {
    #pragma unroll
    for (int ks2 = 0; ks2 < 2; ++ks2) {
      const float* qp =
          Q + base + (p * 128 + wave * 16 + c) * 512 + ks2 * 32 + g * 8;
      float4 a = *reinterpret_cast<const float4*>(qp);
      float4 b = *reinterpret_cast<const float4*>(qp + 4);
      union { unsigned u[4]; short8 s; } t;
      t.u[0] = cvt_pk(a.x * SCQ, a.y * SCQ);
      t.u[1] = cvt_pk(a.z * SCQ, a.w * SCQ);
      t.u[2] = cvt_pk(b.x * SCQ, b.y * SCQ);
      t.u[3] = cvt_pk(b.z * SCQ, b.w * SCQ);
      qf[p][ks2] = t.s;
    }
  }
  __syncthreads();

#define KREAD(t, half) \
  (*reinterpret_cast<const short8*>(&Klds[((t) * 16 + c) * KSTR + (half) * 32 + g * 8]))
#define VREAD(dt, ks) \
  (*reinterpret_cast<const short8*>(reinterpret_cast<const short*>( \
      &Vt32[((dt) * 16 + c) * VSTRW + \
            (((ks) * 16 + 4 * g) ^ (16 * ((dt) & 1) + (c & 12)))])))

  floatx4 ao[2][4];
  #pragma unroll
  for (int p = 0; p < 2; ++p)
    #pragma unroll
    for (int dt = 0; dt < 4; ++dt) ao[p][dt] = floatx4{0.f, 0.f, 0.f, 0.f};
  float ps[2][4] = {{0.f, 0.f, 0.f, 0.f}, {0.f, 0.f, 0.f, 0.f}};

  const int ksW = wave & 7;   // per-wave stagger: de-convoy LDS access
  short8 kfa = KREAD(2 * ksW, 0);
  short8 kfb = KREAD(2 * ksW, 1);

  #pragma unroll
  for (int kk = 0; kk < 8; ++kk) {
    const int ks  = (kk + ksW) & 7;
    const int ksn = (ks + 1) & 7;
    unsigned pk2[2][2][2];   // [pass][tt][m]

    // -- unit tt=0 (t = 2ks): consume kfa/kfb, prefetch t = 2ks+1 --
    {
      short8 ka = kfa, kb = kfb;
      kfa = KREAD(2 * ks + 1, 0);
      kfb = KREAD(2 * ks + 1, 1);
      #pragma unroll
      for (int p = 0; p < 2; ++p) {
        floatx4 z = {0.f, 0.f, 0.f, 0.f};
        floatx4 a0 = __builtin_amdgcn_mfma_f32_16x16x32_bf16(ka, qf[p][0], z, 0, 0, 0);
        floatx4 a1 = __builtin_amdgcn_mfma_f32_16x16x32_bf16(kb, qf[p][1], z, 0, 0, 0);
        float e0 = exp2f(a0[0] + a1[0]);
        float e1 = exp2f(a0[1] + a1[1]);
        float e2 = exp2f(a0[2] + a1[2]);
        float e3 = exp2f(a0[3] + a1[3]);
        ps[p][0] += e0; ps[p][1] += e1; ps[p][2] += e2; ps[p][3] += e3;
        pk2[p][0][0] = cvt_pk(e0, e1);
        pk2[p][0][1] = cvt_pk(e2, e3);
      }
    }

    // -- V prefetch for this ks (latency hidden under tt=1 compute) --
    short8 vf0 = VREAD(0, ks);
    short8 vf1 = VREAD(1, ks);
    short8 vf2 = VREAD(2, ks);
    short8 vf3 = VREAD(3, ks);

    // -- unit tt=1 (t = 2ks+1): consume kfa/kfb, prefetch next unit --
    {
      short8 ka = kfa, kb = kfb;
      kfa = KREAD(2 * ksn, 0);
      kfb = KREAD(2 * ksn, 1);
      #pragma unroll
      for (int p = 0; p < 2; ++p) {
        floatx4 z = {0.f, 0.f, 0.f, 0.f};
        floatx4 a0 = __builtin_amdgcn_mfma_f32_16x16x32_bf16(ka, qf[p][0], z, 0, 0, 0);
        floatx4 a1 = __builtin_amdgcn_mfma_f32_16x16x32_bf16(kb, qf[p][1], z, 0, 0, 0);
        float e0 = exp2f(a0[0] + a1[0]);
        float e1 = exp2f(a0[1] + a1[1]);
        float e2 = exp2f(a0[2] + a1[2]);
        float e3 = exp2f(a0[3] + a1[3]);
        ps[p][0] += e0; ps[p][1] += e1; ps[p][2] += e2; ps[p][3] += e3;
        pk2[p][1][0] = cvt_pk(e0, e1);
        pk2[p][1][1] = cvt_pk(e2, e3);
      }
    }

    // -- P exchange on the VALU pipe (permlane32/16 swap) --
    union { unsigned u[4]; short8 s; } pa[2];
    #pragma unroll
    for (int p = 0; p < 2; ++p) {
      #pragma unroll
      for (int m = 0; m < 2; ++m) {
        unsigned x = pk2[p][0][m], y = pk2[p][1][m];
        asm("v_permlane32_swap_b32 %0, %1" : "+v"(x), "+v"(y));
        asm("v_permlane16_swap_b32 %0, %1" : "+v"(x), "+v"(y));
        pa[p].u[m]     = x;
        pa[p].u[2 + m] = y;
      }
    }

    // -- PV for this s-chunk: V fragments feed both passes --
    ao[0][0] = __builtin_amdgcn_mfma_f32_16x16x32_bf16(pa[0].s, vf0, ao[0][0], 0, 0, 0);
    ao[1][0] = __builtin_amdgcn_mfma_f32_16x16x32_bf16(pa[1].s, vf0, ao[1][0], 0, 0, 0);
    ao[0][1] = __builtin_amdgcn_mfma_f32_16x16x32_bf16(pa[0].s, vf1, ao[0][1], 0, 0, 0);
    ao[1][1] = __builtin_amdgcn_mfma_f32_16x16x32_bf16(pa[1].s, vf1, ao[1][1], 0, 0, 0);
    ao[0][2] = __builtin_amdgcn_mfma_f32_16x16x32_bf16(pa[0].s, vf2, ao[0][2], 0, 0, 0);
    ao[1][2] = __builtin_amdgcn_mfma_f32_16x16x32_bf16(pa[1].s, vf2, ao[1][2], 0, 0, 0);
    ao[0][3] = __builtin_amdgcn_mfma_f32_16x16x32_bf16(pa[0].s, vf3, ao[0][3], 0, 0, 0);
    ao[1][3] = __builtin_amdgcn_mfma_f32_16x16x32_bf16(pa[1].s, vf3, ao[1][3], 0, 0, 0);
  }

  // ---- softmax denominators + epilogue (plain stores; L2 write-combines) ----
  #pragma unroll
  for (int p = 0; p < 2; ++p) {
    const int n0 = p * 128 + wave * 16;
    float sum = (ps[p][0] + ps[p][1]) + (ps[p][2] + ps[p][3]);
    sum += __shfl_xor(sum, 16);
    sum += __shfl_xor(sum, 32);
    const float rcp = __builtin_amdgcn_rcpf(sum);
    float rcpv[4];
    #pragma unroll
    for (int r = 0; r < 4; ++r) rcpv[r] = __shfl(rcp, 4 * g + r);
    #pragma unroll
    for (int dt = 0; dt < 4; ++dt)
      #pragma unroll
      for (int r = 0; r < 4; ++r)
        O[base + (n0 + 4 * g + r) * 512 + dt * 16 + c] = ao[p][dt][r] * rcpv[r];
  }
#undef KREAD
#undef VREAD
}

extern "C" void kernel_launch(void* const* d_in, const int* in_sizes, int n_in,
                              void* d_out, int out_size, void* d_ws, size_t ws_size,
                              hipStream_t stream) {
  const float* Q = (const float*)d_in[0];
  const float* K = (const float*)d_in[1];
  const float* V = (const float*)d_in[2];
  float* O = (float*)d_out;
  attn_kernel<<<dim3(512), dim3(512), 0, stream>>>(Q, K, V, O);
}